// Round 10
// baseline (222.621 us; speedup 1.0000x reference)
//
#include <hip/hip_runtime.h>
#include <hip/hip_bf16.h>
#include <hip/hip_fp16.h>

#define N_NODES 100000
#define D 64
#define N_EDGES 1250000

// fine buckets (sortgather granularity)
#define RB 64                   // nodes per fine bucket (dst>>6)
#define NB 1563                 // ceil(N / 64)
#define FCAP 1536               // fine slab capacity; mean 800, max ~950
#define SORT_CAP 1536

// coarse buckets (partition pass A)
#define CB_SHIFT 11             // 2048 nodes per coarse bucket
#define NCB 49                  // ceil(N / 2048)
#define CCAP 28672              // mean 25510, +20 sigma
#define FINE_PER_COARSE 32      // 2048/64

#define CPAD 16                 // cursor padding: one counter per 64B line

#define EPB 4096                // r8 config (best total, 140.7)
#define PARTA_BLOCKS ((N_EDGES + EPB - 1) / EPB)   // 306
#define SEGS 16
#define SEG_CAP 1792

#define TN 64
#define PRE_BLOCKS 1563
#define FUSED_BLOCKS (PARTA_BLOCKS + PRE_BLOCKS)

#define XP 72                   // LDS fp16 row stride (64 + 8 pad)
#define SMEM_BYTES 27648        // union: pre 27,648; partA 2,560+16,384

// ---- ROUND-10 ALLOCATION ROUND: r7's inflation surfaced only part_kernel;
// pre and sg have never produced a rocprof row, leaving +/-15us ambiguity on
// the two largest pieces. Inflate ALL THREE past the 43.5us fill floor.
// True cost = dur / REP. Config otherwise byte-identical to r8 (best, 140.7).
#define PP_REP 3                // pre_part: 2 scratch + 1 real (partA); pre idempotent
#define PB_REP 8                // partB: 7 scratch + 1 real
#define SG_REP 2                // sortgather: idempotent

typedef unsigned short ushort_t;
typedef _Float16 half_t;
typedef __attribute__((ext_vector_type(8))) _Float16 half8;
typedef __attribute__((ext_vector_type(4))) float floatx4;

// ---------------------------------------------------------------------------
// Fused pre-transform + partition pass A (r8 bodies, x PP_REP).
// ---------------------------------------------------------------------------
__global__ __launch_bounds__(256) void pre_part_kernel(
    const float* __restrict__ x, const float* __restrict__ W_l,
    const float* __restrict__ b_l, const float* __restrict__ W_r,
    ushort_t* __restrict__ y, ushort_t* __restrict__ z,
    const int* __restrict__ src, const int* __restrict__ dst,
    int* __restrict__ ccursor, unsigned* __restrict__ coarse,
    int* __restrict__ cc_s, unsigned* __restrict__ coarse_s,
    int N, int E)
{
    extern __shared__ char smem[];
    int t = threadIdx.x;

    if (blockIdx.x < PARTA_BLOCKS) {
        // ---------------- partA role ----------------
        int* hist4        = (int*)smem;
        int* lbase        = (int*)(smem + 1024);
        int* gbase        = (int*)(smem + 1280);
        int* lwb          = (int*)(smem + 1536);
        unsigned* sortedL = (unsigned*)(smem + 2560); // [EPB] 16,384 B
        const int w = t >> 6;

        int base = blockIdx.x * EPB;
        int lim = E - base; if (lim > EPB) lim = EPB;

        for (int rep = 0; rep < PP_REP; rep++) {
            int* cc      = (rep < PP_REP - 1) ? (cc_s + rep * NCB * CPAD) : ccursor;
            unsigned* co = (rep < PP_REP - 1) ? coarse_s : coarse;

            if (t < 4 * NCB) hist4[t] = 0;
            __syncthreads();

            for (int i = t; i < lim; i += 256)
                atomicAdd(&hist4[w * NCB + (dst[base + i] >> CB_SHIFT)], 1);
            __syncthreads();

            if (t < 64) {
                int c0 = 0, c1 = 0, c2 = 0, c3 = 0, tot = 0;
                if (t < NCB) {
                    c0 = hist4[t]; c1 = hist4[NCB + t];
                    c2 = hist4[2 * NCB + t]; c3 = hist4[3 * NCB + t];
                    tot = c0 + c1 + c2 + c3;
                }
                int inc = tot;
#pragma unroll
                for (int off = 1; off < 64; off <<= 1) {
                    int n = __shfl_up(inc, off, 64);
                    if (t >= off) inc += n;
                }
                int ex = inc - tot;
                if (t < NCB) {
                    lbase[t] = ex;
                    gbase[t] = tot ? atomicAdd(&cc[t * CPAD], tot) : 0;
                    lwb[t]           = ex;
                    lwb[NCB + t]     = ex + c0;
                    lwb[2 * NCB + t] = ex + c0 + c1;
                    lwb[3 * NCB + t] = ex + c0 + c1 + c2;
                } else {
                    lbase[t] = lim;   // sentinel for binary search
                }
            }
            __syncthreads();

            for (int i = t; i < lim; i += 256) {
                int d = dst[base + i];
                int s = src[base + i];
                int b = d >> CB_SHIFT;
                int pos = atomicSub(&hist4[w * NCB + b], 1) - 1;
                sortedL[lwb[w * NCB + b] + pos] =
                    (unsigned)s | ((unsigned)(d & ((1 << CB_SHIFT) - 1)) << 17);
            }
            __syncthreads();

            for (int i = t; i < lim; i += 256) {
                int lo = 0;
#pragma unroll
                for (int s2 = 32; s2; s2 >>= 1) {
                    int c = lo + s2;
                    if (c < 64 && lbase[c] <= i) lo = c;
                }
                co[(size_t)lo * CCAP + gbase[lo] + (i - lbase[lo])] = sortedL[i];
            }
            __syncthreads();   // sortedL reused next rep
        }
        return;
    }

    // ---------------- pre role (x PP_REP, idempotent) ----------------
    half_t* sWt = (half_t*)smem;            // [128*XP] 18,432 B
    half_t* sXh = (half_t*)(smem + 18432);  // [TN*XP]; reused as Y/Z stage

    for (int i = t; i < 64 * 64; i += 256) {
        int k = i >> 6, c = i & 63;
        sWt[c * XP + k]        = (half_t)W_l[i];
        sWt[(64 + c) * XP + k] = (half_t)W_r[i];
    }

    const int lane  = t & 63;
    const int w     = t >> 6;
    const int col16 = lane & 15;
    const int quad  = lane >> 4;

    float4 bq[4];
#pragma unroll
    for (int j = 0; j < 4; j++) bq[j] = *(const float4*)(b_l + j * 16 + quad * 4);

    long base = (long)(blockIdx.x - PARTA_BLOCKS) * TN;

    for (int rep = 0; rep < PP_REP; rep++) {
        __syncthreads();   // W ready / prior Z sweep done

        for (int i = t; i < TN * 16; i += 256) {
            int n = i >> 4, q = i & 15;
            long node = base + n;
            float4 v = make_float4(0.f, 0.f, 0.f, 0.f);
            if (node < N) v = ((const float4*)(x + node * D))[q];
            half_t* p = &sXh[n * XP + q * 4];
            p[0] = (half_t)v.x; p[1] = (half_t)v.y;
            p[2] = (half_t)v.z; p[3] = (half_t)v.w;
        }
        __syncthreads();

        const int nrow = w * 16 + col16;
        half8 xb0 = *(half8*)&sXh[nrow * XP + quad * 8];
        half8 xb1 = *(half8*)&sXh[nrow * XP + 32 + quad * 8];

        // Y: ct 0..3 (stage into own rows; same-wave DS ordering)
#pragma unroll
        for (int ct = 0; ct < 4; ct++) {
            int c = ct * 16 + col16;
            half8 wa0 = *(half8*)&sWt[c * XP + quad * 8];
            half8 wa1 = *(half8*)&sWt[c * XP + 32 + quad * 8];
            floatx4 acc = {0.f, 0.f, 0.f, 0.f};
            acc = __builtin_amdgcn_mfma_f32_16x16x32_f16(wa0, xb0, acc, 0, 0, 0);
            acc = __builtin_amdgcn_mfma_f32_16x16x32_f16(wa1, xb1, acc, 0, 0, 0);
            union { half_t h[4]; uint2 u; } pk;
            pk.h[0] = (half_t)acc[0]; pk.h[1] = (half_t)acc[1];
            pk.h[2] = (half_t)acc[2]; pk.h[3] = (half_t)acc[3];
            *(uint2*)&sXh[(w * 16 + col16) * XP + ct * 16 + quad * 4] = pk.u;
        }
        __syncthreads();

        for (int c2 = t; c2 < TN * 8; c2 += 256) {
            int row = c2 >> 3, f = c2 & 7;
            if (base + row < N)
                *(uint4*)(y + (base + row) * D + f * 8) = *(uint4*)&sXh[row * XP + f * 8];
        }
        __syncthreads();

        // Z: ct 4..7 with bias
#pragma unroll
        for (int ct = 4; ct < 8; ct++) {
            int c = ct * 16 + col16;
            half8 wa0 = *(half8*)&sWt[c * XP + quad * 8];
            half8 wa1 = *(half8*)&sWt[c * XP + 32 + quad * 8];
            floatx4 acc = {0.f, 0.f, 0.f, 0.f};
            acc = __builtin_amdgcn_mfma_f32_16x16x32_f16(wa0, xb0, acc, 0, 0, 0);
            acc = __builtin_amdgcn_mfma_f32_16x16x32_f16(wa1, xb1, acc, 0, 0, 0);
            float4 bv = bq[ct - 4];
            union { half_t h[4]; uint2 u; } pk;
            pk.h[0] = (half_t)(acc[0] + bv.x); pk.h[1] = (half_t)(acc[1] + bv.y);
            pk.h[2] = (half_t)(acc[2] + bv.z); pk.h[3] = (half_t)(acc[3] + bv.w);
            *(uint2*)&sXh[(w * 16 + col16) * XP + (ct - 4) * 16 + quad * 4] = pk.u;
        }
        __syncthreads();

        for (int c2 = t; c2 < TN * 8; c2 += 256) {
            int row = c2 >> 3, f = c2 & 7;
            if (base + row < N)
                *(uint4*)(z + (base + row) * D + f * 8) = *(uint4*)&sXh[row * XP + f * 8];
        }
    }
}

// ---------------------------------------------------------------------------
// Partition pass B (r8 body, x PB_REP): reps 0..6 -> per-rep scratch fcursor
// + scratch fine slab (positions stay < FCAP); rep 7 -> real.
// ---------------------------------------------------------------------------
__global__ __launch_bounds__(256) void partB_kernel(
    const unsigned* __restrict__ coarse, const int* __restrict__ ccursor,
    int* __restrict__ fcursor, unsigned* __restrict__ fine,
    int* __restrict__ fc_s, unsigned* __restrict__ fine_s)
{
    __shared__ int hist4[4 * FINE_PER_COARSE];
    __shared__ int lbase2[FINE_PER_COARSE];
    __shared__ int gbase2[FINE_PER_COARSE];
    __shared__ int lwb2[4 * FINE_PER_COARSE];
    __shared__ unsigned sortedL[SEG_CAP];

    int cb = blockIdx.x >> 4;
    int seg = blockIdx.x & 15;
    int t = threadIdx.x;
    const int w = t >> 6;

    int cnt = ccursor[cb * CPAD];
    int segLen = (cnt + SEGS - 1) / SEGS;
    int beg = seg * segLen;
    int end = beg + segLen; if (end > cnt) end = cnt;
    int lim = end - beg; if (lim < 0) lim = 0;

    const unsigned* __restrict__ slab = coarse + (size_t)cb * CCAP + beg;

    for (int rep = 0; rep < PB_REP; rep++) {
        int* fc      = (rep < PB_REP - 1) ? (fc_s + rep * NB * CPAD) : fcursor;
        unsigned* fo = (rep < PB_REP - 1) ? fine_s : fine;

        if (t < 4 * FINE_PER_COARSE) hist4[t] = 0;
        __syncthreads();

        for (int i = t; i < lim; i += 256)
            atomicAdd(&hist4[w * FINE_PER_COARSE + ((slab[i] >> 17) >> 6)], 1);
        __syncthreads();

        if (t < 64) {
            int c0 = 0, c1 = 0, c2 = 0, c3 = 0, tot = 0;
            if (t < FINE_PER_COARSE) {
                c0 = hist4[t]; c1 = hist4[FINE_PER_COARSE + t];
                c2 = hist4[2 * FINE_PER_COARSE + t]; c3 = hist4[3 * FINE_PER_COARSE + t];
                tot = c0 + c1 + c2 + c3;
            }
            int inc = tot;
#pragma unroll
            for (int off = 1; off < 32; off <<= 1) {
                int n = __shfl_up(inc, off, 64);
                if (t >= off) inc += n;
            }
            int ex = inc - tot;
            if (t < FINE_PER_COARSE) {
                lbase2[t] = ex;
                int fb = cb * FINE_PER_COARSE + t;
                gbase2[t] = tot ? atomicAdd(&fc[fb * CPAD], tot) : 0;
                lwb2[t]                       = ex;
                lwb2[FINE_PER_COARSE + t]     = ex + c0;
                lwb2[2 * FINE_PER_COARSE + t] = ex + c0 + c1;
                lwb2[3 * FINE_PER_COARSE + t] = ex + c0 + c1 + c2;
            }
        }
        __syncthreads();

        for (int i = t; i < lim; i += 256) {
            unsigned e = slab[i];
            unsigned cl = e >> 17;
            int loc = cl >> 6;
            int pos = atomicSub(&hist4[w * FINE_PER_COARSE + loc], 1) - 1;
            sortedL[lwb2[w * FINE_PER_COARSE + loc] + pos] =
                (e & 0x1FFFFu) | ((cl & 63u) << 17);
        }
        __syncthreads();

        for (int i = t; i < lim; i += 256) {
            int lo = 0;
#pragma unroll
            for (int s2 = 16; s2; s2 >>= 1) {
                int c = lo + s2;
                if (c < FINE_PER_COARSE && lbase2[c] <= i) lo = c;
            }
            fo[((size_t)cb * FINE_PER_COARSE + lo) * FCAP + gbase2[lo] + (i - lbase2[lo])]
                = sortedL[i];
        }
        __syncthreads();   // sortedL reused next rep
    }
}

// ---------------------------------------------------------------------------
// Fused sort + gather (r8 body with 8-deep unroll, x SG_REP idempotent).
// ---------------------------------------------------------------------------
__global__ __launch_bounds__(512) void sortgather_kernel(
    const ushort_t* __restrict__ y, const ushort_t* __restrict__ z,
    const unsigned* __restrict__ part, const int* __restrict__ cursor,
    float* __restrict__ out, int N)
{
    __shared__ int sorted[SORT_CAP];
    __shared__ int hist[RB];
    __shared__ int cur[RB];
    __shared__ int begL[RB];

    int b = blockIdx.x;
    int t = threadIdx.x;
    int cnt = cursor[b * CPAD];
    if (cnt > SORT_CAP) cnt = SORT_CAP;
    const unsigned* __restrict__ slab = part + (size_t)b * FCAP;

    for (int rep = 0; rep < SG_REP; rep++) {
        __syncthreads();   // prior rep's gather done before hist reset

        unsigned e0 = 0, e1 = 0, e2 = 0;
        int i0 = t, i1 = t + 512, i2 = t + 1024;
        if (i0 < cnt) e0 = slab[i0];
        if (i1 < cnt) e1 = slab[i1];
        if (i2 < cnt) e2 = slab[i2];

        if (t < RB) hist[t] = 0;
        __syncthreads();

        if (i0 < cnt) atomicAdd(&hist[e0 >> 17], 1);
        if (i1 < cnt) atomicAdd(&hist[e1 >> 17], 1);
        if (i2 < cnt) atomicAdd(&hist[e2 >> 17], 1);
        __syncthreads();

        if (t < RB) {
            int v = hist[t];
            int inc = v;
#pragma unroll
            for (int off = 1; off < RB; off <<= 1) {
                int n = __shfl_up(inc, off, RB);
                if (t >= off) inc += n;
            }
            int ex = inc - v;
            cur[t] = ex;
            begL[t] = ex;
        }
        __syncthreads();

        if (i0 < cnt) { int p = atomicAdd(&cur[e0 >> 17], 1); sorted[p] = (int)(e0 & 0x1FFFF); }
        if (i1 < cnt) { int p = atomicAdd(&cur[e1 >> 17], 1); sorted[p] = (int)(e1 & 0x1FFFF); }
        if (i2 < cnt) { int p = atomicAdd(&cur[e2 >> 17], 1); sorted[p] = (int)(e2 & 0x1FFFF); }
        __syncthreads();

        const int g = t >> 3;
        const int f = t & 7;
        int myBeg = begL[g];
        int myDeg = hist[g];

        float2 acc0 = make_float2(0.f, 0.f), acc1 = acc0, acc2 = acc0, acc3 = acc0;

#define ACC(r) { \
        float2 c0 = __half22float2(*(const __half2*)&(r).x); \
        float2 c1 = __half22float2(*(const __half2*)&(r).y); \
        float2 c2 = __half22float2(*(const __half2*)&(r).z); \
        float2 c3 = __half22float2(*(const __half2*)&(r).w); \
        acc0.x += c0.x; acc0.y += c0.y; acc1.x += c1.x; acc1.y += c1.y; \
        acc2.x += c2.x; acc2.y += c2.y; acc3.x += c3.x; acc3.y += c3.y; }

        int i = 0;
        for (; i + 8 <= myDeg; i += 8) {
            int s0 = sorted[myBeg + i];
            int s1 = sorted[myBeg + i + 1];
            int s2 = sorted[myBeg + i + 2];
            int s3 = sorted[myBeg + i + 3];
            int s4 = sorted[myBeg + i + 4];
            int s5 = sorted[myBeg + i + 5];
            int s6 = sorted[myBeg + i + 6];
            int s7 = sorted[myBeg + i + 7];
            uint4 r0 = ((const uint4*)(y + (size_t)s0 * D))[f];
            uint4 r1 = ((const uint4*)(y + (size_t)s1 * D))[f];
            uint4 r2 = ((const uint4*)(y + (size_t)s2 * D))[f];
            uint4 r3 = ((const uint4*)(y + (size_t)s3 * D))[f];
            uint4 r4 = ((const uint4*)(y + (size_t)s4 * D))[f];
            uint4 r5 = ((const uint4*)(y + (size_t)s5 * D))[f];
            uint4 r6 = ((const uint4*)(y + (size_t)s6 * D))[f];
            uint4 r7 = ((const uint4*)(y + (size_t)s7 * D))[f];
            ACC(r0) ACC(r1) ACC(r2) ACC(r3) ACC(r4) ACC(r5) ACC(r6) ACC(r7)
        }
        for (; i + 4 <= myDeg; i += 4) {
            int s0 = sorted[myBeg + i];
            int s1 = sorted[myBeg + i + 1];
            int s2 = sorted[myBeg + i + 2];
            int s3 = sorted[myBeg + i + 3];
            uint4 r0 = ((const uint4*)(y + (size_t)s0 * D))[f];
            uint4 r1 = ((const uint4*)(y + (size_t)s1 * D))[f];
            uint4 r2 = ((const uint4*)(y + (size_t)s2 * D))[f];
            uint4 r3 = ((const uint4*)(y + (size_t)s3 * D))[f];
            ACC(r0) ACC(r1) ACC(r2) ACC(r3)
        }
        for (; i < myDeg; i++) {
            int s = sorted[myBeg + i];
            uint4 r = ((const uint4*)(y + (size_t)s * D))[f];
            ACC(r)
        }
#undef ACC

        long gn = (long)b * RB + g;
        if (gn < N) {
            uint4 zr = ((const uint4*)(z + (size_t)gn * D))[f];
            float2 z0 = __half22float2(*(const __half2*)&zr.x);
            float2 z1 = __half22float2(*(const __half2*)&zr.y);
            float2 z2 = __half22float2(*(const __half2*)&zr.z);
            float2 z3 = __half22float2(*(const __half2*)&zr.w);
            float4 o0, o1;
            o0.x = tanhf(acc0.x + z0.x); o0.y = tanhf(acc0.y + z0.y);
            o0.z = tanhf(acc1.x + z1.x); o0.w = tanhf(acc1.y + z1.y);
            o1.x = tanhf(acc2.x + z2.x); o1.y = tanhf(acc2.y + z2.y);
            o1.z = tanhf(acc3.x + z3.x); o1.w = tanhf(acc3.y + z3.y);
            float4* op = (float4*)(out + gn * D);
            op[2 * f] = o0;
            op[2 * f + 1] = o1;
        }
    }
}

extern "C" void kernel_launch(void* const* d_in, const int* in_sizes, int n_in,
                              void* d_out, int out_size, void* d_ws, size_t ws_size,
                              hipStream_t stream) {
    const float* x   = (const float*)d_in[0];
    const int* ei    = (const int*)d_in[1];   // [2,E] int32
    const float* W_l = (const float*)d_in[2];
    const float* b_l = (const float*)d_in[3];
    const float* W_r = (const float*)d_in[4];
    float* out = (float*)d_out;

    const int N = N_NODES;
    const int E = N_EDGES;
    const int* src = ei;
    const int* dst = ei + E;

    // workspace layout (ws is 268 MB)
    char* ws = (char*)d_ws;
    ushort_t* y        = (ushort_t*)(ws);                  // 12,800,000 B
    ushort_t* z        = (ushort_t*)(ws + 12800000);       // 12,800,000 B
    unsigned* coarse   = (unsigned*)(ws + 25600000);       // 5,619,712 B
    unsigned* fine     = (unsigned*)(ws + 31219712);       // 9,603,072 B
    int* ccursor       = (int*)(ws + 40822784);            // 3,136 B
    int* fcursor       = (int*)(ws + 40825920);            // 100,032 B
    int* cc_s          = (int*)(ws + 40925952);            // 2 x 3,136 B
    int* fc_s          = (int*)(ws + 40932224);            // 7 x 100,032 B
    unsigned* coarse_s = (unsigned*)(ws + 41632448);       // 5,619,712 B
    unsigned* fine_s   = (unsigned*)(ws + 47252160);       // 9,603,072 B

    // zero all cursor arrays: ccursor..fc_s end is one contiguous region
    // 40,822,784 .. 41,632,448 = 809,664 B
    hipMemsetAsync(ccursor, 0, 809664, stream);

    pre_part_kernel<<<FUSED_BLOCKS, 256, SMEM_BYTES, stream>>>(
        x, W_l, b_l, W_r, y, z, src, dst, ccursor, coarse, cc_s, coarse_s, N, E);
    partB_kernel<<<NCB * SEGS, 256, 0, stream>>>(
        coarse, ccursor, fcursor, fine, fc_s, fine_s);
    sortgather_kernel<<<NB, 512, 0, stream>>>(y, z, fine, fcursor, out, N);
}

// Round 11
// 138.745 us; speedup vs baseline: 1.6045x; 1.6045x over previous
//
#include <hip/hip_runtime.h>
#include <hip/hip_bf16.h>
#include <hip/hip_fp16.h>

#define N_NODES 100000
#define D 64
#define N_EDGES 1250000

// fine buckets (sortgather granularity)
#define RB 64                   // nodes per fine bucket (dst>>6)
#define NB 1563                 // ceil(N / 64)
#define FCAP 1536               // fine slab capacity; mean 800, max ~950
#define SORT_CAP 1536

// coarse buckets (partition pass A)
#define CB_SHIFT 11             // 2048 nodes per coarse bucket
#define NCB 49                  // ceil(N / 2048)
#define CCAP 28672              // mean 25510, +20 sigma
#define FINE_PER_COARSE 32      // 2048/64

#define CPAD 16                 // cursor padding: one counter per 64B line

// ROUND-10 ATTRIBUTION (measured): pre_part=20.2us, partB~2us, sg=27.5us,
// harness overhead ~91us (2x 43.5us full-ws poison fills). Levers are
// residency: sg had 1563 blocks vs 1024 slots (half-idle 2nd round);
// partA wall time = its serial pass chain at 256 threads.
#define EPB 8192                // partA: 1024 thr -> 8 iters/pass, 153 blocks
#define PARTA_BLOCKS ((N_EDGES + EPB - 1) / EPB)   // 153
#define SEGS 16
#define SEG_CAP 1792

#define TNP 256                 // pre nodes per 1024-thread block
#define PRE_BLOCKS ((N_NODES + TNP - 1) / TNP)     // 391
#define FUSED_BLOCKS (PARTA_BLOCKS + PRE_BLOCKS)   // 544 (~1 round at 2/CU)

#define NWAVE 16                // waves per fused block

#define XP 72                   // LDS fp16 row stride (64 + 8 pad)
// smem union: pre = 18,432(W) + 256*72*2(X/stage) = 55,296 B (2 blocks/CU)
//             partA = 6,912 + 32,768 = 39,680 B
#define SMEM_BYTES 55296

#define SG_BPB 2                // sortgather buckets per block
#define SG_BLOCKS ((NB + SG_BPB - 1) / SG_BPB)     // 782 (all resident)

typedef unsigned short ushort_t;
typedef _Float16 half_t;
typedef __attribute__((ext_vector_type(8))) _Float16 half8;
typedef __attribute__((ext_vector_type(4))) float floatx4;

// ---------------------------------------------------------------------------
// Fused pre-transform + partition pass A, 1024-thread blocks.
// partA role (blocks 0..152): 16 waves over 8192 edges (8 iters/pass) ->
//   per-wave LDS hist, wave-0 scan + padded cursor reserve, LDS counting
//   sort, coalesced sweep (runs ~167 entries = 668 B).
// pre role (blocks 153..): 256 nodes/block; [Y|Z] = X @ [W_l|W_r] fp16 MFMA;
//   W staged once per 256 nodes (4x less W traffic); LDS-staged 128-B-row
//   output sweeps.
// ---------------------------------------------------------------------------
__global__ __launch_bounds__(1024) void pre_part_kernel(
    const float* __restrict__ x, const float* __restrict__ W_l,
    const float* __restrict__ b_l, const float* __restrict__ W_r,
    ushort_t* __restrict__ y, ushort_t* __restrict__ z,
    const int* __restrict__ src, const int* __restrict__ dst,
    int* __restrict__ ccursor, unsigned* __restrict__ coarse,
    int N, int E)
{
    extern __shared__ char smem[];
    int t = threadIdx.x;

    if (blockIdx.x < PARTA_BLOCKS) {
        // ---------------- partA role ----------------
        int* hist16       = (int*)smem;               // [16][NCB] 3,136 B
        int* lbase        = (int*)(smem + 3200);      // [64] local excl base
        int* gbase        = (int*)(smem + 3456);      // [NCB]
        int* lwb          = (int*)(smem + 3712);      // [16][NCB] 3,136 B
        unsigned* sortedL = (unsigned*)(smem + 6912); // [EPB] 32,768 B
        const int w = t >> 6;

        if (t < NWAVE * NCB) hist16[t] = 0;
        __syncthreads();

        int base = blockIdx.x * EPB;
        int lim = E - base; if (lim > EPB) lim = EPB;

        for (int i = t; i < lim; i += 1024)
            atomicAdd(&hist16[w * NCB + (dst[base + i] >> CB_SHIFT)], 1);
        __syncthreads();

        if (t < 64) {   // lane-parallel scan + global reserve
            int cw[NWAVE]; int tot = 0;
            if (t < NCB) {
#pragma unroll
                for (int k = 0; k < NWAVE; k++) { cw[k] = hist16[k * NCB + t]; tot += cw[k]; }
            }
            int inc = tot;
#pragma unroll
            for (int off = 1; off < 64; off <<= 1) {
                int n = __shfl_up(inc, off, 64);
                if (t >= off) inc += n;
            }
            int ex = inc - tot;
            if (t < NCB) {
                lbase[t] = ex;
                gbase[t] = tot ? atomicAdd(&ccursor[t * CPAD], tot) : 0;
                int run = ex;
#pragma unroll
                for (int k = 0; k < NWAVE; k++) { lwb[k * NCB + t] = run; run += cw[k]; }
            } else {
                lbase[t] = lim;   // sentinel for binary search
            }
        }
        __syncthreads();

        for (int i = t; i < lim; i += 1024) {
            int d = dst[base + i];
            int s = src[base + i];
            int b = d >> CB_SHIFT;
            int pos = atomicSub(&hist16[w * NCB + b], 1) - 1;
            sortedL[lwb[w * NCB + b] + pos] =
                (unsigned)s | ((unsigned)(d & ((1 << CB_SHIFT) - 1)) << 17);
        }
        __syncthreads();

        // sweep: element i -> bucket = max b with lbase[b] <= i
        for (int i = t; i < lim; i += 1024) {
            int lo = 0;
#pragma unroll
            for (int s2 = 32; s2; s2 >>= 1) {
                int c = lo + s2;
                if (c < 64 && lbase[c] <= i) lo = c;
            }
            coarse[(size_t)lo * CCAP + gbase[lo] + (i - lbase[lo])] = sortedL[i];
        }
        return;
    }

    // ---------------- pre role (256 nodes, MFMA, LDS-staged output) --------
    half_t* sWt = (half_t*)smem;            // [128*XP] 18,432 B
    half_t* sXh = (half_t*)(smem + 18432);  // [TNP*XP] 36,864 B; Y/Z stage

    for (int i = t; i < 64 * 64; i += 1024) {
        int k = i >> 6, c = i & 63;
        sWt[c * XP + k]        = (half_t)W_l[i];
        sWt[(64 + c) * XP + k] = (half_t)W_r[i];
    }

    long base = (long)(blockIdx.x - PARTA_BLOCKS) * TNP;
    for (int i = t; i < TNP * 16; i += 1024) {   // 256 nodes x 16 float4
        int n = i >> 4, q = i & 15;
        long node = base + n;
        float4 v = make_float4(0.f, 0.f, 0.f, 0.f);
        if (node < N) v = ((const float4*)(x + node * D))[q];
        half_t* p = &sXh[n * XP + q * 4];
        p[0] = (half_t)v.x; p[1] = (half_t)v.y;
        p[2] = (half_t)v.z; p[3] = (half_t)v.w;
    }
    __syncthreads();

    const int lane  = t & 63;
    const int w     = t >> 6;        // wave id = node-tile 0..15
    const int col16 = lane & 15;
    const int quad  = lane >> 4;

    const int nrow = w * 16 + col16;
    half8 xb0 = *(half8*)&sXh[nrow * XP + quad * 8];
    half8 xb1 = *(half8*)&sXh[nrow * XP + 32 + quad * 8];

    float4 bq[4];
#pragma unroll
    for (int j = 0; j < 4; j++) bq[j] = *(const float4*)(b_l + j * 16 + quad * 4);

    // Y: ct 0..3 (stage into own rows; same-wave DS ordering)
#pragma unroll
    for (int ct = 0; ct < 4; ct++) {
        int c = ct * 16 + col16;
        half8 wa0 = *(half8*)&sWt[c * XP + quad * 8];
        half8 wa1 = *(half8*)&sWt[c * XP + 32 + quad * 8];
        floatx4 acc = {0.f, 0.f, 0.f, 0.f};
        acc = __builtin_amdgcn_mfma_f32_16x16x32_f16(wa0, xb0, acc, 0, 0, 0);
        acc = __builtin_amdgcn_mfma_f32_16x16x32_f16(wa1, xb1, acc, 0, 0, 0);
        union { half_t h[4]; uint2 u; } pk;
        pk.h[0] = (half_t)acc[0]; pk.h[1] = (half_t)acc[1];
        pk.h[2] = (half_t)acc[2]; pk.h[3] = (half_t)acc[3];
        *(uint2*)&sXh[nrow * XP + ct * 16 + quad * 4] = pk.u;
    }
    __syncthreads();

    for (int c2 = t; c2 < TNP * 8; c2 += 1024) {
        int row = c2 >> 3, f = c2 & 7;
        if (base + row < N)
            *(uint4*)(y + (base + row) * D + f * 8) = *(uint4*)&sXh[row * XP + f * 8];
    }
    __syncthreads();

    // Z: ct 4..7 with bias
#pragma unroll
    for (int ct = 4; ct < 8; ct++) {
        int c = ct * 16 + col16;
        half8 wa0 = *(half8*)&sWt[c * XP + quad * 8];
        half8 wa1 = *(half8*)&sWt[c * XP + 32 + quad * 8];
        floatx4 acc = {0.f, 0.f, 0.f, 0.f};
        acc = __builtin_amdgcn_mfma_f32_16x16x32_f16(wa0, xb0, acc, 0, 0, 0);
        acc = __builtin_amdgcn_mfma_f32_16x16x32_f16(wa1, xb1, acc, 0, 0, 0);
        float4 bv = bq[ct - 4];
        union { half_t h[4]; uint2 u; } pk;
        pk.h[0] = (half_t)(acc[0] + bv.x); pk.h[1] = (half_t)(acc[1] + bv.y);
        pk.h[2] = (half_t)(acc[2] + bv.z); pk.h[3] = (half_t)(acc[3] + bv.w);
        *(uint2*)&sXh[nrow * XP + (ct - 4) * 16 + quad * 4] = pk.u;
    }
    __syncthreads();

    for (int c2 = t; c2 < TNP * 8; c2 += 1024) {
        int row = c2 >> 3, f = c2 & 7;
        if (base + row < N)
            *(uint4*)(z + (base + row) * D + f * 8) = *(uint4*)&sXh[row * XP + f * 8];
    }
}

// ---------------------------------------------------------------------------
// Partition pass B (r8 form, measured ~2us): 16 segment-blocks per coarse
// bucket; LDS sort + coalesced sweep. Repacks src | fineLocal<<17.
// ---------------------------------------------------------------------------
__global__ __launch_bounds__(256) void partB_kernel(
    const unsigned* __restrict__ coarse, const int* __restrict__ ccursor,
    int* __restrict__ fcursor, unsigned* __restrict__ fine)
{
    __shared__ int hist4[4 * FINE_PER_COARSE];
    __shared__ int lbase2[FINE_PER_COARSE];
    __shared__ int gbase2[FINE_PER_COARSE];
    __shared__ int lwb2[4 * FINE_PER_COARSE];
    __shared__ unsigned sortedL[SEG_CAP];

    int cb = blockIdx.x >> 4;
    int seg = blockIdx.x & 15;
    int t = threadIdx.x;
    const int w = t >> 6;

    int cnt = ccursor[cb * CPAD];
    int segLen = (cnt + SEGS - 1) / SEGS;
    int beg = seg * segLen;
    int end = beg + segLen; if (end > cnt) end = cnt;
    int lim = end - beg; if (lim < 0) lim = 0;

    if (t < 4 * FINE_PER_COARSE) hist4[t] = 0;
    __syncthreads();

    const unsigned* __restrict__ slab = coarse + (size_t)cb * CCAP + beg;

    for (int i = t; i < lim; i += 256)
        atomicAdd(&hist4[w * FINE_PER_COARSE + ((slab[i] >> 17) >> 6)], 1);
    __syncthreads();

    if (t < 64) {
        int c0 = 0, c1 = 0, c2 = 0, c3 = 0, tot = 0;
        if (t < FINE_PER_COARSE) {
            c0 = hist4[t]; c1 = hist4[FINE_PER_COARSE + t];
            c2 = hist4[2 * FINE_PER_COARSE + t]; c3 = hist4[3 * FINE_PER_COARSE + t];
            tot = c0 + c1 + c2 + c3;
        }
        int inc = tot;
#pragma unroll
        for (int off = 1; off < 32; off <<= 1) {
            int n = __shfl_up(inc, off, 64);
            if (t >= off) inc += n;
        }
        int ex = inc - tot;
        if (t < FINE_PER_COARSE) {
            lbase2[t] = ex;
            int fb = cb * FINE_PER_COARSE + t;
            gbase2[t] = tot ? atomicAdd(&fcursor[fb * CPAD], tot) : 0;
            lwb2[t]                       = ex;
            lwb2[FINE_PER_COARSE + t]     = ex + c0;
            lwb2[2 * FINE_PER_COARSE + t] = ex + c0 + c1;
            lwb2[3 * FINE_PER_COARSE + t] = ex + c0 + c1 + c2;
        }
    }
    __syncthreads();

    for (int i = t; i < lim; i += 256) {
        unsigned e = slab[i];
        unsigned cl = e >> 17;
        int loc = cl >> 6;
        int pos = atomicSub(&hist4[w * FINE_PER_COARSE + loc], 1) - 1;
        sortedL[lwb2[w * FINE_PER_COARSE + loc] + pos] =
            (e & 0x1FFFFu) | ((cl & 63u) << 17);
    }
    __syncthreads();

    for (int i = t; i < lim; i += 256) {
        int lo = 0;
#pragma unroll
        for (int s2 = 16; s2; s2 >>= 1) {
            int c = lo + s2;
            if (c < FINE_PER_COARSE && lbase2[c] <= i) lo = c;
        }
        fine[((size_t)cb * FINE_PER_COARSE + lo) * FCAP + gbase2[lo] + (i - lbase2[lo])]
            = sortedL[i];
    }
}

// ---------------------------------------------------------------------------
// Fused sort + gather: 782 blocks x 2 buckets (ROUND-10: 1563 blocks vs 1024
// residency slots left a half-idle second round, Occ 58%). All 782 blocks
// now resident -> no dispatch tail. Bucket sizes ~800+-28, uniform.
// ---------------------------------------------------------------------------
__global__ __launch_bounds__(512) void sortgather_kernel(
    const ushort_t* __restrict__ y, const ushort_t* __restrict__ z,
    const unsigned* __restrict__ part, const int* __restrict__ cursor,
    float* __restrict__ out, int N)
{
    __shared__ int sorted[SORT_CAP];
    __shared__ int hist[RB];
    __shared__ int cur[RB];
    __shared__ int begL[RB];

    int t = threadIdx.x;

    for (int sub = 0; sub < SG_BPB; sub++) {
        int b = blockIdx.x * SG_BPB + sub;
        if (b >= NB) break;
        __syncthreads();   // prior bucket's gather done before LDS reuse

        int cnt = cursor[b * CPAD];
        if (cnt > SORT_CAP) cnt = SORT_CAP;
        const unsigned* __restrict__ slab = part + (size_t)b * FCAP;

        unsigned e0 = 0, e1 = 0, e2 = 0;
        int i0 = t, i1 = t + 512, i2 = t + 1024;
        if (i0 < cnt) e0 = slab[i0];
        if (i1 < cnt) e1 = slab[i1];
        if (i2 < cnt) e2 = slab[i2];

        if (t < RB) hist[t] = 0;
        __syncthreads();

        if (i0 < cnt) atomicAdd(&hist[e0 >> 17], 1);
        if (i1 < cnt) atomicAdd(&hist[e1 >> 17], 1);
        if (i2 < cnt) atomicAdd(&hist[e2 >> 17], 1);
        __syncthreads();

        if (t < RB) {
            int v = hist[t];
            int inc = v;
#pragma unroll
            for (int off = 1; off < RB; off <<= 1) {
                int n = __shfl_up(inc, off, RB);
                if (t >= off) inc += n;
            }
            int ex = inc - v;
            cur[t] = ex;
            begL[t] = ex;
        }
        __syncthreads();

        if (i0 < cnt) { int p = atomicAdd(&cur[e0 >> 17], 1); sorted[p] = (int)(e0 & 0x1FFFF); }
        if (i1 < cnt) { int p = atomicAdd(&cur[e1 >> 17], 1); sorted[p] = (int)(e1 & 0x1FFFF); }
        if (i2 < cnt) { int p = atomicAdd(&cur[e2 >> 17], 1); sorted[p] = (int)(e2 & 0x1FFFF); }
        __syncthreads();

        const int g = t >> 3;
        const int f = t & 7;
        int myBeg = begL[g];
        int myDeg = hist[g];

        float2 acc0 = make_float2(0.f, 0.f), acc1 = acc0, acc2 = acc0, acc3 = acc0;

#define ACC(r) { \
        float2 c0 = __half22float2(*(const __half2*)&(r).x); \
        float2 c1 = __half22float2(*(const __half2*)&(r).y); \
        float2 c2 = __half22float2(*(const __half2*)&(r).z); \
        float2 c3 = __half22float2(*(const __half2*)&(r).w); \
        acc0.x += c0.x; acc0.y += c0.y; acc1.x += c1.x; acc1.y += c1.y; \
        acc2.x += c2.x; acc2.y += c2.y; acc3.x += c3.x; acc3.y += c3.y; }

        int i = 0;
        for (; i + 8 <= myDeg; i += 8) {
            int s0 = sorted[myBeg + i];
            int s1 = sorted[myBeg + i + 1];
            int s2 = sorted[myBeg + i + 2];
            int s3 = sorted[myBeg + i + 3];
            int s4 = sorted[myBeg + i + 4];
            int s5 = sorted[myBeg + i + 5];
            int s6 = sorted[myBeg + i + 6];
            int s7 = sorted[myBeg + i + 7];
            uint4 r0 = ((const uint4*)(y + (size_t)s0 * D))[f];
            uint4 r1 = ((const uint4*)(y + (size_t)s1 * D))[f];
            uint4 r2 = ((const uint4*)(y + (size_t)s2 * D))[f];
            uint4 r3 = ((const uint4*)(y + (size_t)s3 * D))[f];
            uint4 r4 = ((const uint4*)(y + (size_t)s4 * D))[f];
            uint4 r5 = ((const uint4*)(y + (size_t)s5 * D))[f];
            uint4 r6 = ((const uint4*)(y + (size_t)s6 * D))[f];
            uint4 r7 = ((const uint4*)(y + (size_t)s7 * D))[f];
            ACC(r0) ACC(r1) ACC(r2) ACC(r3) ACC(r4) ACC(r5) ACC(r6) ACC(r7)
        }
        for (; i + 4 <= myDeg; i += 4) {
            int s0 = sorted[myBeg + i];
            int s1 = sorted[myBeg + i + 1];
            int s2 = sorted[myBeg + i + 2];
            int s3 = sorted[myBeg + i + 3];
            uint4 r0 = ((const uint4*)(y + (size_t)s0 * D))[f];
            uint4 r1 = ((const uint4*)(y + (size_t)s1 * D))[f];
            uint4 r2 = ((const uint4*)(y + (size_t)s2 * D))[f];
            uint4 r3 = ((const uint4*)(y + (size_t)s3 * D))[f];
            ACC(r0) ACC(r1) ACC(r2) ACC(r3)
        }
        for (; i < myDeg; i++) {
            int s = sorted[myBeg + i];
            uint4 r = ((const uint4*)(y + (size_t)s * D))[f];
            ACC(r)
        }
#undef ACC

        long gn = (long)b * RB + g;
        if (gn < N) {
            uint4 zr = ((const uint4*)(z + (size_t)gn * D))[f];
            float2 z0 = __half22float2(*(const __half2*)&zr.x);
            float2 z1 = __half22float2(*(const __half2*)&zr.y);
            float2 z2 = __half22float2(*(const __half2*)&zr.z);
            float2 z3 = __half22float2(*(const __half2*)&zr.w);
            float4 o0, o1;
            o0.x = tanhf(acc0.x + z0.x); o0.y = tanhf(acc0.y + z0.y);
            o0.z = tanhf(acc1.x + z1.x); o0.w = tanhf(acc1.y + z1.y);
            o1.x = tanhf(acc2.x + z2.x); o1.y = tanhf(acc2.y + z2.y);
            o1.z = tanhf(acc3.x + z3.x); o1.w = tanhf(acc3.y + z3.y);
            float4* op = (float4*)(out + gn * D);
            op[2 * f] = o0;
            op[2 * f + 1] = o1;
        }
    }
}

extern "C" void kernel_launch(void* const* d_in, const int* in_sizes, int n_in,
                              void* d_out, int out_size, void* d_ws, size_t ws_size,
                              hipStream_t stream) {
    const float* x   = (const float*)d_in[0];
    const int* ei    = (const int*)d_in[1];   // [2,E] int32
    const float* W_l = (const float*)d_in[2];
    const float* b_l = (const float*)d_in[3];
    const float* W_r = (const float*)d_in[4];
    float* out = (float*)d_out;

    const int N = N_NODES;
    const int E = N_EDGES;
    const int* src = ei;
    const int* dst = ei + E;

    // workspace layout (ws is 268 MB)
    char* ws = (char*)d_ws;
    ushort_t* y      = (ushort_t*)(ws);                  // 12,800,000 B
    ushort_t* z      = (ushort_t*)(ws + 12800000);       // 12,800,000 B
    unsigned* coarse = (unsigned*)(ws + 25600000);       // 5,619,712 B
    unsigned* fine   = (unsigned*)(ws + 31219712);       // 9,603,072 B
    int* ccursor     = (int*)(ws + 40822784);            // 3,136 B (line-padded)
    int* fcursor     = (int*)(ws + 40825920);            // 100,032 B (line-padded)

    // zero both padded cursor arrays (adjacent): 3,136 + 100,032 B
    hipMemsetAsync(ccursor, 0, 103168, stream);

    pre_part_kernel<<<FUSED_BLOCKS, 1024, SMEM_BYTES, stream>>>(
        x, W_l, b_l, W_r, y, z, src, dst, ccursor, coarse, N, E);
    partB_kernel<<<NCB * SEGS, 256, 0, stream>>>(coarse, ccursor, fcursor, fine);
    sortgather_kernel<<<SG_BLOCKS, 512, 0, stream>>>(y, z, fine, fcursor, out, N);
}